// Round 8
// baseline (283.739 us; speedup 1.0000x reference)
//
#include <hip/hip_runtime.h>

#define NNODES 100000
#define NEDGES 800000
#define NGRAPHS 5000
#define FN 11
#define FE 4
#define H1C 32
#define H2C 16

typedef _Float16 half8 __attribute__((ext_vector_type(8)));
typedef _Float16 half2v __attribute__((ext_vector_type(2)));
typedef float f32x4 __attribute__((ext_vector_type(4)));

// agg1[n,o] = c1_bias[o] + sum_i x[n,i]*c1_root[i,o]
__global__ __launch_bounds__(256) void k_init1(const float* __restrict__ x,
    const float* __restrict__ root, const float* __restrict__ bias,
    float* __restrict__ agg1) {
  int t = blockIdx.x * 256 + threadIdx.x;
  int n = t >> 5, o = t & 31;
  if (n >= NNODES) return;
  float acc = bias[o];
  #pragma unroll
  for (int i = 0; i < FN; i++) acc += x[n * FN + i] * root[i * H1C + o];
  agg1[n * H1C + o] = acc;
}

// Pre-swizzled f16 B-fragments for conv1 MFMA (same index math verified r5).
__global__ __launch_bounds__(256) void k_prepB1(const float* __restrict__ w2,
    const float* __restrict__ b2, _Float16* __restrict__ B1h) {
  int t = blockIdx.x * 256 + threadIdx.x;
  if (t >= 2 * 12 * 64 * 8) return;
  int j = t & 7;
  int lane = (t >> 3) & 63;
  int rest = t >> 9;
  int step = rest % 12;
  int ot = rest / 12;
  int q = (lane >> 4) * 8 + j;
  int o = (lane & 15) + ot * 16;
  float v;
  if (step < 11) v = w2[q * (FN * H1C) + step * H1C + o];
  else v = (q < FN) ? b2[q * H1C + o] : 0.f;
  B1h[t] = (_Float16)v;
}

// conv1 edge pass via MFMA. B-frags read from GLOBAL (L1-resident, off the
// LDS pipe); fp16 A-frags built with packed muls. LDS 25 KB -> 6 blocks/CU.
__global__ __launch_bounds__(256, 6) void k_edge1_mfma(
    const float* __restrict__ x, const int* __restrict__ ei,
    const float* __restrict__ ea, const float* __restrict__ w1,
    const float* __restrict__ b1, const _Float16* __restrict__ B1h,
    float* __restrict__ agg1) {
  __shared__ _Float16 h_sl[4][256][8];    // 16 KB h slices
  __shared__ _Float16 xs_sl[2][256][8];   // 8 KB xs slices (slices 2,3 all-zero)
  __shared__ int s_dst[256];
  int tid = threadIdx.x;
  int e = blockIdx.x * 256 + tid;   // NEDGES % 256 == 0
  int src = ei[e];
  s_dst[tid] = ei[NEDGES + e];
  float4 a4 = *reinterpret_cast<const float4*>(ea + e * 4);
  float h[32];
  #pragma unroll
  for (int k = 0; k < 32; k++) {
    float v = b1[k] + a4.x * w1[k] + a4.y * w1[32 + k] + a4.z * w1[64 + k] + a4.w * w1[96 + k];
    h[k] = v > 0.f ? v : 0.f;
  }
  #pragma unroll
  for (int s = 0; s < 4; s++) {
    half8 t8;
    #pragma unroll
    for (int j = 0; j < 8; j++) t8[j] = (_Float16)h[s * 8 + j];
    *reinterpret_cast<half8*>(&h_sl[s][tid][0]) = t8;
  }
  float xsv[FN];
  #pragma unroll
  for (int i = 0; i < FN; i++) xsv[i] = x[src * FN + i];
  #pragma unroll
  for (int s = 0; s < 2; s++) {
    half8 t8;
    #pragma unroll
    for (int j = 0; j < 8; j++) {
      int k = s * 8 + j;
      t8[j] = (k < FN) ? (_Float16)xsv[k] : (_Float16)0.f;
    }
    *reinterpret_cast<half8*>(&xs_sl[s][tid][0]) = t8;
  }
  __syncthreads();
  int lane = tid & 63;
  int w = tid >> 6;
  int halfk = lane >> 4;
  int er = lane & 15;
  #pragma unroll 1
  for (int g = 0; g < 4; g++) {
    int eb = w * 64 + g * 16;
    int el = eb + er;
    half8 hs8 = *reinterpret_cast<const half8*>(&h_sl[halfk][el][0]);
    half8 xs8;
    if (halfk < 2) xs8 = *reinterpret_cast<const half8*>(&xs_sl[halfk][el][0]);
    else xs8 = half8{};   // K rows 16..31 of the bias step are zero
    f32x4 acc0 = {0.f, 0.f, 0.f, 0.f};
    f32x4 acc1 = {0.f, 0.f, 0.f, 0.f};
    {
      half8 b0 = *reinterpret_cast<const half8*>(&B1h[11 * 512 + lane * 8]);
      half8 b1f = *reinterpret_cast<const half8*>(&B1h[6144 + 11 * 512 + lane * 8]);
      acc0 = __builtin_amdgcn_mfma_f32_16x16x32_f16(xs8, b0, acc0, 0, 0, 0);
      acc1 = __builtin_amdgcn_mfma_f32_16x16x32_f16(xs8, b1f, acc1, 0, 0, 0);
    }
    #pragma unroll
    for (int i = 0; i < FN; i++) {
      _Float16 xh = xs_sl[i >> 3][el][i & 7];
      half8 xsp;
      #pragma unroll
      for (int j = 0; j < 8; j++) xsp[j] = xh;
      half8 af = xsp * hs8;            // 4x v_pk_mul_f16
      half8 b0 = *reinterpret_cast<const half8*>(&B1h[i * 512 + lane * 8]);
      half8 b1f = *reinterpret_cast<const half8*>(&B1h[6144 + i * 512 + lane * 8]);
      acc0 = __builtin_amdgcn_mfma_f32_16x16x32_f16(af, b0, acc0, 0, 0, 0);
      acc1 = __builtin_amdgcn_mfma_f32_16x16x32_f16(af, b1f, acc1, 0, 0, 0);
    }
    #pragma unroll
    for (int r = 0; r < 4; r++) {
      int d = s_dst[eb + halfk * 4 + r];
      atomicAdd(&agg1[d * H1C + er], acc0[r]);
      atomicAdd(&agg1[d * H1C + er + 16], acc1[r]);
    }
  }
}

// h1h = f16(relu(agg1)); agg2[n,o] = c2_bias[o] + sum_i relu(agg1)[n,i]*c2_root[i,o]
__global__ __launch_bounds__(256) void k_mid(const float* __restrict__ agg1,
    const float* __restrict__ root2, const float* __restrict__ bias2,
    _Float16* __restrict__ h1h, float* __restrict__ agg2) {
  int t = blockIdx.x * 256 + threadIdx.x;
  int n = t >> 4, o = t & 15;
  if (n >= NNODES) return;
  float hv[32];
  #pragma unroll
  for (int i = 0; i < 32; i++) {
    float v = agg1[n * H1C + i];
    hv[i] = v > 0.f ? v : 0.f;
  }
  h1h[n * H1C + o] = (_Float16)hv[o];
  h1h[n * H1C + o + 16] = (_Float16)hv[o + 16];
  float acc = bias2[o];
  #pragma unroll
  for (int i = 0; i < 32; i++) acc += hv[i] * root2[i * H2C + o];
  agg2[n * H2C + o] = acc;
}

// Pre-swizzled f16 B-fragments for conv2 MFMA (index math verified r4).
__global__ __launch_bounds__(256) void k_prepB2(const float* __restrict__ w2,
    _Float16* __restrict__ B2h) {
  int t = blockIdx.x * 256 + threadIdx.x;
  if (t >= 32 * 64 * 8) return;
  int kk = t >> 9;
  int l = (t >> 3) & 63;
  int j = t & 7;
  int i = (l >> 4) * 8 + j;
  int o = l & 15;
  B2h[t] = (_Float16)w2[(kk * 32 + i) * H2C + o];
}

// conv2 edge pass via MFMA. Global B-frags + fp16 packed A-frag build.
// LDS 19 KB; VGPR-capped at 4 blocks/CU.
__global__ __launch_bounds__(256, 4) void k_edge2_mfma(
    const _Float16* __restrict__ h1h, const int* __restrict__ ei,
    const float* __restrict__ ea, const float* __restrict__ w1,
    const float* __restrict__ b1, const _Float16* __restrict__ B2h,
    float* __restrict__ agg2) {
  __shared__ _Float16 h_lds[256][34];    // 17 KB (pad 34 -> conflict-free u16 reads)
  __shared__ int s_src[256];
  __shared__ int s_dst[256];
  int tid = threadIdx.x;
  int e = blockIdx.x * 256 + tid;
  s_src[tid] = ei[e];
  s_dst[tid] = ei[NEDGES + e];
  float4 a4 = *reinterpret_cast<const float4*>(ea + e * 4);
  #pragma unroll
  for (int k = 0; k < 32; k++) {
    float v = b1[k] + a4.x * w1[k] + a4.y * w1[32 + k] + a4.z * w1[64 + k] + a4.w * w1[96 + k];
    h_lds[tid][k] = (_Float16)(v > 0.f ? v : 0.f);
  }
  __syncthreads();
  int lane = tid & 63;
  int w = tid >> 6;
  int halfk = lane >> 4;
  int er = lane & 15;
  #pragma unroll 1
  for (int g = 0; g < 4; g++) {
    int eb = w * 64 + g * 16;
    int el = eb + er;
    int sn = s_src[el];
    half8 hsb = *reinterpret_cast<const half8*>(h1h + sn * H1C + halfk * 8);
    f32x4 acc = {0.f, 0.f, 0.f, 0.f};
    #pragma unroll
    for (int kk = 0; kk < 32; kk++) {
      _Float16 hv = h_lds[el][kk];
      half8 hsp;
      #pragma unroll
      for (int j = 0; j < 8; j++) hsp[j] = hv;
      half8 af = hsp * hsb;            // 4x v_pk_mul_f16
      half8 bfrag = *reinterpret_cast<const half8*>(&B2h[(kk * 64 + lane) * 8]);
      acc = __builtin_amdgcn_mfma_f32_16x16x32_f16(af, bfrag, acc, 0, 0, 0);
    }
    #pragma unroll
    for (int r = 0; r < 4; r++) {
      int row = halfk * 4 + r;
      int d = s_dst[eb + row];
      atomicAdd(&agg2[d * H2C + er], acc[r]);
    }
  }
}

// pooled[batch[n],o] += relu(agg2[n,o])
__global__ __launch_bounds__(256) void k_pool(const float* __restrict__ agg2,
    const int* __restrict__ batch, float* __restrict__ pooled) {
  int t = blockIdx.x * 256 + threadIdx.x;
  int n = t >> 4, o = t & 15;
  if (n >= NNODES) return;
  float v = agg2[n * H2C + o];
  v = v > 0.f ? v : 0.f;
  atomicAdd(&pooled[batch[n] * H2C + o], v);
}

// out[g] = relu(pooled[g]@fc1_w + fc1_b) @ out_w + out_b
__global__ __launch_bounds__(256) void k_head(const float* __restrict__ pooled,
    const float* __restrict__ fc1w, const float* __restrict__ fc1b,
    const float* __restrict__ outw, const float* __restrict__ outb,
    float* __restrict__ out) {
  int g = blockIdx.x * 256 + threadIdx.x;
  if (g >= NGRAPHS) return;
  float p[H2C];
  #pragma unroll
  for (int i = 0; i < H2C; i++) p[i] = pooled[g * H2C + i];
  float acc = outb[0];
  #pragma unroll
  for (int o = 0; o < H1C; o++) {
    float v = fc1b[o];
    #pragma unroll
    for (int i = 0; i < H2C; i++) v += p[i] * fc1w[i * H1C + o];
    v = v > 0.f ? v : 0.f;
    acc += v * outw[o];
  }
  out[g] = acc;
}

extern "C" void kernel_launch(void* const* d_in, const int* in_sizes, int n_in,
                              void* d_out, int out_size, void* d_ws, size_t ws_size,
                              hipStream_t stream) {
  const float* x      = (const float*)d_in[0];
  const int*   ei     = (const int*)d_in[1];
  const float* ea     = (const float*)d_in[2];
  const int*   batch  = (const int*)d_in[3];
  const float* c1w1   = (const float*)d_in[4];
  const float* c1b1   = (const float*)d_in[5];
  const float* c1w2   = (const float*)d_in[6];
  const float* c1b2   = (const float*)d_in[7];
  const float* c1root = (const float*)d_in[8];
  const float* c1bias = (const float*)d_in[9];
  const float* c2w1   = (const float*)d_in[10];
  const float* c2b1   = (const float*)d_in[11];
  const float* c2w2   = (const float*)d_in[12];
  const float* c2b2   = (const float*)d_in[13];
  const float* c2root = (const float*)d_in[14];
  const float* c2bias = (const float*)d_in[15];
  const float* fc1w   = (const float*)d_in[16];
  const float* fc1b   = (const float*)d_in[17];
  const float* outw   = (const float*)d_in[18];
  const float* outb   = (const float*)d_in[19];
  float* out = (float*)d_out;

  float*     agg1   = (float*)d_ws;                       // 12.8 MB
  _Float16*  h1h    = (_Float16*)(agg1 + NNODES * H1C);   // 6.4 MB
  float*     agg2   = (float*)(h1h + NNODES * H1C);       // 6.4 MB
  float*     pooled = agg2 + NNODES * H2C;                // 320 KB
  _Float16*  B2h    = (_Float16*)(pooled + NGRAPHS * H2C);// 32 KB
  _Float16*  B1h    = B2h + 32 * 64 * 8;                  // 24 KB

  hipMemsetAsync(pooled, 0, NGRAPHS * H2C * sizeof(float), stream);

  k_init1<<<(NNODES * H1C + 255) / 256, 256, 0, stream>>>(x, c1root, c1bias, agg1);
  k_prepB1<<<48, 256, 0, stream>>>(c1w2, c1b2, B1h);
  k_prepB2<<<64, 256, 0, stream>>>(c2w2, B2h);
  k_edge1_mfma<<<NEDGES / 256, 256, 0, stream>>>(x, ei, ea, c1w1, c1b1, B1h, agg1);
  k_mid<<<(NNODES * H2C + 255) / 256, 256, 0, stream>>>(agg1, c2root, c2bias, h1h, agg2);
  k_edge2_mfma<<<NEDGES / 256, 256, 0, stream>>>(h1h, ei, ea, c2w1, c2b1, B2h, agg2);
  k_pool<<<(NNODES * H2C + 255) / 256, 256, 0, stream>>>(agg2, batch, pooled);
  k_head<<<(NGRAPHS + 255) / 256, 256, 0, stream>>>(pooled, fc1w, fc1b, outw, outb, out);
}

// Round 9
// 240.916 us; speedup vs baseline: 1.1778x; 1.1778x over previous
//
#include <hip/hip_runtime.h>

#define NNODES 100000
#define NEDGES 800000
#define NGRAPHS 5000
#define FN 11
#define FE 4
#define H1C 32
#define H2C 16

typedef _Float16 half8 __attribute__((ext_vector_type(8)));
typedef float f32x4 __attribute__((ext_vector_type(4)));

// agg1[n,o] = c1_bias[o] + sum_i x[n,i]*c1_root[i,o]
__global__ __launch_bounds__(256) void k_init1(const float* __restrict__ x,
    const float* __restrict__ root, const float* __restrict__ bias,
    float* __restrict__ agg1) {
  int t = blockIdx.x * 256 + threadIdx.x;
  int n = t >> 5, o = t & 31;
  if (n >= NNODES) return;
  float acc = bias[o];
  #pragma unroll
  for (int i = 0; i < FN; i++) acc += x[n * FN + i] * root[i * H1C + o];
  agg1[n * H1C + o] = acc;
}

// Pre-swizzled f16 B-fragments for conv1 MFMA (index math verified r5).
__global__ __launch_bounds__(256) void k_prepB1(const float* __restrict__ w2,
    const float* __restrict__ b2, _Float16* __restrict__ B1h) {
  int t = blockIdx.x * 256 + threadIdx.x;
  if (t >= 2 * 12 * 64 * 8) return;
  int j = t & 7;
  int lane = (t >> 3) & 63;
  int rest = t >> 9;
  int step = rest % 12;
  int ot = rest / 12;
  int q = (lane >> 4) * 8 + j;
  int o = (lane & 15) + ot * 16;
  float v;
  if (step < 11) v = w2[q * (FN * H1C) + step * H1C + o];
  else v = (q < FN) ? b2[q * H1C + o] : 0.f;
  B1h[t] = (_Float16)v;
}

// conv1 edge pass via MFMA. LDS B-frags (r7) + fp16 packed A-build (r8) +
// per-lane h-slice recompute (drops the 16 KB h_sl transpose).
// LDS ~35 KB -> 4 blocks/CU.
__global__ __launch_bounds__(256, 4) void k_edge1_mfma(
    const float* __restrict__ x, const int* __restrict__ ei,
    const float* __restrict__ ea, const float* __restrict__ w1,
    const float* __restrict__ b1, const _Float16* __restrict__ B1h,
    float* __restrict__ agg1) {
  __shared__ _Float16 Bl[12288];        // 24 KB B-frags
  __shared__ _Float16 xs_sl[256][18];   // 9 KB, pad 18 -> 9*el mod 32 permutation
  __shared__ float w1s[128];
  __shared__ float b1s[32];
  __shared__ int s_dst[256];
  int tid = threadIdx.x;
  {
    const int4* s = (const int4*)B1h;   // 1536 int4
    int4* d = (int4*)Bl;
    #pragma unroll
    for (int q = 0; q < 6; q++) d[q * 256 + tid] = s[q * 256 + tid];
  }
  if (tid < 128) w1s[tid] = w1[tid];
  if (tid < 32) b1s[tid] = b1[tid];
  int e = blockIdx.x * 256 + tid;   // NEDGES % 256 == 0
  int src = ei[e];
  s_dst[tid] = ei[NEDGES + e];
  {
    float xsv[FN];
    #pragma unroll
    for (int i = 0; i < FN; i++) xsv[i] = x[src * FN + i];
    #pragma unroll
    for (int i = 0; i < FN; i++) xs_sl[tid][i] = (_Float16)xsv[i];
    #pragma unroll
    for (int i = FN; i < 16; i++) xs_sl[tid][i] = (_Float16)0.f;
  }
  __syncthreads();
  int lane = tid & 63;
  int w = tid >> 6;
  int halfk = lane >> 4;
  int er = lane & 15;
  int kbase = halfk * 8;
  #pragma unroll 1
  for (int g = 0; g < 4; g++) {
    int eb = w * 64 + g * 16;
    int el = eb + er;
    float4 a4 = *reinterpret_cast<const float4*>(ea + (size_t)(blockIdx.x * 256 + el) * 4);
    half8 hs8;
    #pragma unroll
    for (int j = 0; j < 8; j++) {
      int k = kbase + j;
      float v = b1s[k] + a4.x * w1s[k] + a4.y * w1s[32 + k] + a4.z * w1s[64 + k] + a4.w * w1s[96 + k];
      hs8[j] = (_Float16)(v > 0.f ? v : 0.f);
    }
    half8 xs8;
    if (halfk < 2) xs8 = *reinterpret_cast<const half8*>(&xs_sl[el][halfk * 8]);
    else xs8 = half8{};   // K rows 16..31 of the bias step are zero
    f32x4 acc0 = {0.f, 0.f, 0.f, 0.f};
    f32x4 acc1 = {0.f, 0.f, 0.f, 0.f};
    {
      half8 b0 = *reinterpret_cast<const half8*>(&Bl[11 * 512 + lane * 8]);
      half8 b1f = *reinterpret_cast<const half8*>(&Bl[6144 + 11 * 512 + lane * 8]);
      acc0 = __builtin_amdgcn_mfma_f32_16x16x32_f16(xs8, b0, acc0, 0, 0, 0);
      acc1 = __builtin_amdgcn_mfma_f32_16x16x32_f16(xs8, b1f, acc1, 0, 0, 0);
    }
    #pragma unroll
    for (int i = 0; i < FN; i++) {
      _Float16 xh = xs_sl[el][i];
      half8 xsp;
      #pragma unroll
      for (int j = 0; j < 8; j++) xsp[j] = xh;
      half8 af = xsp * hs8;            // v_pk_mul_f16 x4
      half8 b0 = *reinterpret_cast<const half8*>(&Bl[i * 512 + lane * 8]);
      half8 b1f = *reinterpret_cast<const half8*>(&Bl[6144 + i * 512 + lane * 8]);
      acc0 = __builtin_amdgcn_mfma_f32_16x16x32_f16(af, b0, acc0, 0, 0, 0);
      acc1 = __builtin_amdgcn_mfma_f32_16x16x32_f16(af, b1f, acc1, 0, 0, 0);
    }
    #pragma unroll
    for (int r = 0; r < 4; r++) {
      int d = s_dst[eb + halfk * 4 + r];
      atomicAdd(&agg1[d * H1C + er], acc0[r]);
      atomicAdd(&agg1[d * H1C + er + 16], acc1[r]);
    }
  }
}

// h1h = f16(relu(agg1)); agg2[n,o] = c2_bias[o] + sum_i relu(agg1)[n,i]*c2_root[i,o]
__global__ __launch_bounds__(256) void k_mid(const float* __restrict__ agg1,
    const float* __restrict__ root2, const float* __restrict__ bias2,
    _Float16* __restrict__ h1h, float* __restrict__ agg2) {
  int t = blockIdx.x * 256 + threadIdx.x;
  int n = t >> 4, o = t & 15;
  if (n >= NNODES) return;
  float hv[32];
  #pragma unroll
  for (int i = 0; i < 32; i++) {
    float v = agg1[n * H1C + i];
    hv[i] = v > 0.f ? v : 0.f;
  }
  h1h[n * H1C + o] = (_Float16)hv[o];
  h1h[n * H1C + o + 16] = (_Float16)hv[o + 16];
  float acc = bias2[o];
  #pragma unroll
  for (int i = 0; i < 32; i++) acc += hv[i] * root2[i * H2C + o];
  agg2[n * H2C + o] = acc;
}

// Pre-swizzled f16 B-fragments for conv2 MFMA (index math verified r4).
__global__ __launch_bounds__(256) void k_prepB2(const float* __restrict__ w2,
    _Float16* __restrict__ B2h) {
  int t = blockIdx.x * 256 + threadIdx.x;
  if (t >= 32 * 64 * 8) return;
  int kk = t >> 9;
  int l = (t >> 3) & 63;
  int j = t & 7;
  int i = (l >> 4) * 8 + j;
  int o = l & 15;
  B2h[t] = (_Float16)w2[(kk * 32 + i) * H2C + o];
}

// conv2 edge pass via MFMA: r7 LDS-B structure + fp16 packed A-build.
// LDS 51 KB -> 3 blocks/CU.
__global__ __launch_bounds__(256, 3) void k_edge2_mfma(
    const _Float16* __restrict__ h1h, const int* __restrict__ ei,
    const float* __restrict__ ea, const float* __restrict__ w1,
    const float* __restrict__ b1, const _Float16* __restrict__ B2h,
    float* __restrict__ agg2) {
  __shared__ _Float16 Bl[16384];         // 32 KB
  __shared__ _Float16 h_lds[256][34];    // 17 KB (pad 34 -> 17*el mod 32 permutation)
  __shared__ int s_src[256];
  __shared__ int s_dst[256];
  int tid = threadIdx.x;
  {
    const int4* s = (const int4*)B2h;    // 2048 int4
    int4* d = (int4*)Bl;
    #pragma unroll
    for (int q = 0; q < 8; q++) d[q * 256 + tid] = s[q * 256 + tid];
  }
  int e = blockIdx.x * 256 + tid;
  s_src[tid] = ei[e];
  s_dst[tid] = ei[NEDGES + e];
  float4 a4 = *reinterpret_cast<const float4*>(ea + e * 4);
  #pragma unroll
  for (int k = 0; k < 32; k++) {
    float v = b1[k] + a4.x * w1[k] + a4.y * w1[32 + k] + a4.z * w1[64 + k] + a4.w * w1[96 + k];
    h_lds[tid][k] = (_Float16)(v > 0.f ? v : 0.f);
  }
  __syncthreads();
  int lane = tid & 63;
  int w = tid >> 6;
  int halfk = lane >> 4;
  int er = lane & 15;
  #pragma unroll 1
  for (int g = 0; g < 4; g++) {
    int eb = w * 64 + g * 16;
    int el = eb + er;
    int sn = s_src[el];
    half8 hsb = *reinterpret_cast<const half8*>(h1h + sn * H1C + halfk * 8);
    f32x4 acc = {0.f, 0.f, 0.f, 0.f};
    #pragma unroll
    for (int kk = 0; kk < 32; kk++) {
      _Float16 hv = h_lds[el][kk];
      half8 hsp;
      #pragma unroll
      for (int j = 0; j < 8; j++) hsp[j] = hv;
      half8 af = hsp * hsb;            // v_pk_mul_f16 x4
      half8 bfrag = *reinterpret_cast<const half8*>(&Bl[(kk * 64 + lane) * 8]);
      acc = __builtin_amdgcn_mfma_f32_16x16x32_f16(af, bfrag, acc, 0, 0, 0);
    }
    #pragma unroll
    for (int r = 0; r < 4; r++) {
      int row = halfk * 4 + r;
      int d = s_dst[eb + row];
      atomicAdd(&agg2[d * H2C + er], acc[r]);
    }
  }
}

// pooled[batch[n],o] += relu(agg2[n,o])
__global__ __launch_bounds__(256) void k_pool(const float* __restrict__ agg2,
    const int* __restrict__ batch, float* __restrict__ pooled) {
  int t = blockIdx.x * 256 + threadIdx.x;
  int n = t >> 4, o = t & 15;
  if (n >= NNODES) return;
  float v = agg2[n * H2C + o];
  v = v > 0.f ? v : 0.f;
  atomicAdd(&pooled[batch[n] * H2C + o], v);
}

// out[g] = relu(pooled[g]@fc1_w + fc1_b) @ out_w + out_b
__global__ __launch_bounds__(256) void k_head(const float* __restrict__ pooled,
    const float* __restrict__ fc1w, const float* __restrict__ fc1b,
    const float* __restrict__ outw, const float* __restrict__ outb,
    float* __restrict__ out) {
  int g = blockIdx.x * 256 + threadIdx.x;
  if (g >= NGRAPHS) return;
  float p[H2C];
  #pragma unroll
  for (int i = 0; i < H2C; i++) p[i] = pooled[g * H2C + i];
  float acc = outb[0];
  #pragma unroll
  for (int o = 0; o < H1C; o++) {
    float v = fc1b[o];
    #pragma unroll
    for (int i = 0; i < H2C; i++) v += p[i] * fc1w[i * H1C + o];
    v = v > 0.f ? v : 0.f;
    acc += v * outw[o];
  }
  out[g] = acc;
}

extern "C" void kernel_launch(void* const* d_in, const int* in_sizes, int n_in,
                              void* d_out, int out_size, void* d_ws, size_t ws_size,
                              hipStream_t stream) {
  const float* x      = (const float*)d_in[0];
  const int*   ei     = (const int*)d_in[1];
  const float* ea     = (const float*)d_in[2];
  const int*   batch  = (const int*)d_in[3];
  const float* c1w1   = (const float*)d_in[4];
  const float* c1b1   = (const float*)d_in[5];
  const float* c1w2   = (const float*)d_in[6];
  const float* c1b2   = (const float*)d_in[7];
  const float* c1root = (const float*)d_in[8];
  const float* c1bias = (const float*)d_in[9];
  const float* c2w1   = (const float*)d_in[10];
  const float* c2b1   = (const float*)d_in[11];
  const float* c2w2   = (const float*)d_in[12];
  const float* c2b2   = (const float*)d_in[13];
  const float* c2root = (const float*)d_in[14];
  const float* c2bias = (const float*)d_in[15];
  const float* fc1w   = (const float*)d_in[16];
  const float* fc1b   = (const float*)d_in[17];
  const float* outw   = (const float*)d_in[18];
  const float* outb   = (const float*)d_in[19];
  float* out = (float*)d_out;

  float*     agg1   = (float*)d_ws;                       // 12.8 MB
  _Float16*  h1h    = (_Float16*)(agg1 + NNODES * H1C);   // 6.4 MB
  float*     agg2   = (float*)(h1h + NNODES * H1C);       // 6.4 MB
  float*     pooled = agg2 + NNODES * H2C;                // 320 KB
  _Float16*  B2h    = (_Float16*)(pooled + NGRAPHS * H2C);// 32 KB
  _Float16*  B1h    = B2h + 32 * 64 * 8;                  // 24 KB

  hipMemsetAsync(pooled, 0, NGRAPHS * H2C * sizeof(float), stream);

  k_init1<<<(NNODES * H1C + 255) / 256, 256, 0, stream>>>(x, c1root, c1bias, agg1);
  k_prepB1<<<48, 256, 0, stream>>>(c1w2, c1b2, B1h);
  k_prepB2<<<64, 256, 0, stream>>>(c2w2, B2h);
  k_edge1_mfma<<<NEDGES / 256, 256, 0, stream>>>(x, ei, ea, c1w1, c1b1, B1h, agg1);
  k_mid<<<(NNODES * H2C + 255) / 256, 256, 0, stream>>>(agg1, c2root, c2bias, h1h, agg2);
  k_edge2_mfma<<<NEDGES / 256, 256, 0, stream>>>(h1h, ei, ea, c2w1, c2b1, B2h, agg2);
  k_pool<<<(NNODES * H2C + 255) / 256, 256, 0, stream>>>(agg2, batch, pooled);
  k_head<<<(NGRAPHS + 255) / 256, 256, 0, stream>>>(pooled, fc1w, fc1b, outw, outb, out);
}

// Round 10
// 200.172 us; speedup vs baseline: 1.4175x; 1.2035x over previous
//
#include <hip/hip_runtime.h>

#define NNODES 100000
#define NEDGES 800000
#define NGRAPHS 5000
#define FN 11
#define FE 4
#define H1C 32
#define H2C 16

typedef _Float16 half8 __attribute__((ext_vector_type(8)));
typedef float f32x4 __attribute__((ext_vector_type(4)));

// agg1[n,o] = c1_bias[o] + sum_i x[n,i]*c1_root[i,o]
__global__ __launch_bounds__(256) void k_init1(const float* __restrict__ x,
    const float* __restrict__ root, const float* __restrict__ bias,
    float* __restrict__ agg1) {
  int t = blockIdx.x * 256 + threadIdx.x;
  int n = t >> 5, o = t & 31;
  if (n >= NNODES) return;
  float acc = bias[o];
  #pragma unroll
  for (int i = 0; i < FN; i++) acc += x[n * FN + i] * root[i * H1C + o];
  agg1[n * H1C + o] = acc;
}

// Pre-swizzled f16 B-fragments for conv1 MFMA (index math verified r5).
__global__ __launch_bounds__(256) void k_prepB1(const float* __restrict__ w2,
    const float* __restrict__ b2, _Float16* __restrict__ B1h) {
  int t = blockIdx.x * 256 + threadIdx.x;
  if (t >= 2 * 12 * 64 * 8) return;
  int j = t & 7;
  int lane = (t >> 3) & 63;
  int rest = t >> 9;
  int step = rest % 12;
  int ot = rest / 12;
  int q = (lane >> 4) * 8 + j;
  int o = (lane & 15) + ot * 16;
  float v;
  if (step < 11) v = w2[q * (FN * H1C) + step * H1C + o];
  else v = (q < FN) ? b2[q * H1C + o] : 0.f;
  B1h[t] = (_Float16)v;
}

// conv1 edge pass via MFMA — EXACT r7 structure (87 µs, FETCH 33 MB,
// WRITE = payload, no L2 thrash) with the r8-proven fp16 pk_mul A-path.
// LDS 49 KB -> 3 blocks/CU (the measured-good atomic/L2 balance point).
__global__ __launch_bounds__(256, 3) void k_edge1_mfma(
    const float* __restrict__ x, const int* __restrict__ ei,
    const float* __restrict__ ea, const float* __restrict__ w1,
    const float* __restrict__ b1, const _Float16* __restrict__ B1h,
    float* __restrict__ agg1) {
  __shared__ _Float16 Bl[12288];        // 24 KB B-frags
  __shared__ _Float16 h_sl[4][256][8];  // 16 KB h slices
  __shared__ _Float16 xs_sl[2][256][8]; // 8 KB xs slices (slices 2,3 all-zero)
  __shared__ int s_dst[256];
  int tid = threadIdx.x;
  {
    const int4* s = (const int4*)B1h;   // 1536 int4
    int4* d = (int4*)Bl;
    #pragma unroll
    for (int q = 0; q < 6; q++) d[q * 256 + tid] = s[q * 256 + tid];
  }
  int e = blockIdx.x * 256 + tid;   // NEDGES % 256 == 0
  int src = ei[e];
  s_dst[tid] = ei[NEDGES + e];
  float4 a4 = *reinterpret_cast<const float4*>(ea + e * 4);
  float h[32];
  #pragma unroll
  for (int k = 0; k < 32; k++) {
    float v = b1[k] + a4.x * w1[k] + a4.y * w1[32 + k] + a4.z * w1[64 + k] + a4.w * w1[96 + k];
    h[k] = v > 0.f ? v : 0.f;
  }
  #pragma unroll
  for (int s = 0; s < 4; s++) {
    half8 t8;
    #pragma unroll
    for (int j = 0; j < 8; j++) t8[j] = (_Float16)h[s * 8 + j];
    *reinterpret_cast<half8*>(&h_sl[s][tid][0]) = t8;
  }
  float xsv[FN];
  #pragma unroll
  for (int i = 0; i < FN; i++) xsv[i] = x[src * FN + i];
  #pragma unroll
  for (int s = 0; s < 2; s++) {
    half8 t8;
    #pragma unroll
    for (int j = 0; j < 8; j++) {
      int k = s * 8 + j;
      t8[j] = (k < FN) ? (_Float16)xsv[k] : (_Float16)0.f;
    }
    *reinterpret_cast<half8*>(&xs_sl[s][tid][0]) = t8;
  }
  __syncthreads();
  int lane = tid & 63;
  int w = tid >> 6;
  int halfk = lane >> 4;
  int er = lane & 15;
  #pragma unroll 1
  for (int g = 0; g < 4; g++) {
    int eb = w * 64 + g * 16;
    int el = eb + er;
    half8 hs8 = *reinterpret_cast<const half8*>(&h_sl[halfk][el][0]);
    half8 xs8;
    if (halfk < 2) xs8 = *reinterpret_cast<const half8*>(&xs_sl[halfk][el][0]);
    else xs8 = half8{};   // K rows 16..31 of the bias step are zero
    f32x4 acc0 = {0.f, 0.f, 0.f, 0.f};
    f32x4 acc1 = {0.f, 0.f, 0.f, 0.f};
    {
      half8 b0 = *reinterpret_cast<const half8*>(&Bl[11 * 512 + lane * 8]);
      half8 b1f = *reinterpret_cast<const half8*>(&Bl[6144 + 11 * 512 + lane * 8]);
      acc0 = __builtin_amdgcn_mfma_f32_16x16x32_f16(xs8, b0, acc0, 0, 0, 0);
      acc1 = __builtin_amdgcn_mfma_f32_16x16x32_f16(xs8, b1f, acc1, 0, 0, 0);
    }
    #pragma unroll
    for (int i = 0; i < FN; i++) {
      _Float16 xh = xs_sl[i >> 3][el][i & 7];
      half8 xsp;
      #pragma unroll
      for (int j = 0; j < 8; j++) xsp[j] = xh;
      half8 af = xsp * hs8;            // v_pk_mul_f16 x4
      half8 b0 = *reinterpret_cast<const half8*>(&Bl[i * 512 + lane * 8]);
      half8 b1f = *reinterpret_cast<const half8*>(&Bl[6144 + i * 512 + lane * 8]);
      acc0 = __builtin_amdgcn_mfma_f32_16x16x32_f16(af, b0, acc0, 0, 0, 0);
      acc1 = __builtin_amdgcn_mfma_f32_16x16x32_f16(af, b1f, acc1, 0, 0, 0);
    }
    #pragma unroll
    for (int r = 0; r < 4; r++) {
      int d = s_dst[eb + halfk * 4 + r];
      atomicAdd(&agg1[d * H1C + er], acc0[r]);
      atomicAdd(&agg1[d * H1C + er + 16], acc1[r]);
    }
  }
}

// h1h = f16(relu(agg1)); agg2[n,o] = c2_bias[o] + sum_i relu(agg1)[n,i]*c2_root[i,o]
__global__ __launch_bounds__(256) void k_mid(const float* __restrict__ agg1,
    const float* __restrict__ root2, const float* __restrict__ bias2,
    _Float16* __restrict__ h1h, float* __restrict__ agg2) {
  int t = blockIdx.x * 256 + threadIdx.x;
  int n = t >> 4, o = t & 15;
  if (n >= NNODES) return;
  float hv[32];
  #pragma unroll
  for (int i = 0; i < 32; i++) {
    float v = agg1[n * H1C + i];
    hv[i] = v > 0.f ? v : 0.f;
  }
  h1h[n * H1C + o] = (_Float16)hv[o];
  h1h[n * H1C + o + 16] = (_Float16)hv[o + 16];
  float acc = bias2[o];
  #pragma unroll
  for (int i = 0; i < 32; i++) acc += hv[i] * root2[i * H2C + o];
  agg2[n * H2C + o] = acc;
}

// Pre-swizzled f16 B-fragments for conv2 MFMA (index math verified r4).
__global__ __launch_bounds__(256) void k_prepB2(const float* __restrict__ w2,
    _Float16* __restrict__ B2h) {
  int t = blockIdx.x * 256 + threadIdx.x;
  if (t >= 32 * 64 * 8) return;
  int kk = t >> 9;
  int l = (t >> 3) & 63;
  int j = t & 7;
  int i = (l >> 4) * 8 + j;
  int o = l & 15;
  B2h[t] = (_Float16)w2[(kk * 32 + i) * H2C + o];
}

// conv2 edge pass via MFMA: r7 LDS-B structure + fp16 packed A-build.
// LDS 51 KB -> 3 blocks/CU (unchanged from r9; never the top kernel).
__global__ __launch_bounds__(256, 3) void k_edge2_mfma(
    const _Float16* __restrict__ h1h, const int* __restrict__ ei,
    const float* __restrict__ ea, const float* __restrict__ w1,
    const float* __restrict__ b1, const _Float16* __restrict__ B2h,
    float* __restrict__ agg2) {
  __shared__ _Float16 Bl[16384];         // 32 KB
  __shared__ _Float16 h_lds[256][34];    // 17 KB (pad 34 -> conflict-free)
  __shared__ int s_src[256];
  __shared__ int s_dst[256];
  int tid = threadIdx.x;
  {
    const int4* s = (const int4*)B2h;    // 2048 int4
    int4* d = (int4*)Bl;
    #pragma unroll
    for (int q = 0; q < 8; q++) d[q * 256 + tid] = s[q * 256 + tid];
  }
  int e = blockIdx.x * 256 + tid;
  s_src[tid] = ei[e];
  s_dst[tid] = ei[NEDGES + e];
  float4 a4 = *reinterpret_cast<const float4*>(ea + e * 4);
  #pragma unroll
  for (int k = 0; k < 32; k++) {
    float v = b1[k] + a4.x * w1[k] + a4.y * w1[32 + k] + a4.z * w1[64 + k] + a4.w * w1[96 + k];
    h_lds[tid][k] = (_Float16)(v > 0.f ? v : 0.f);
  }
  __syncthreads();
  int lane = tid & 63;
  int w = tid >> 6;
  int halfk = lane >> 4;
  int er = lane & 15;
  #pragma unroll 1
  for (int g = 0; g < 4; g++) {
    int eb = w * 64 + g * 16;
    int el = eb + er;
    int sn = s_src[el];
    half8 hsb = *reinterpret_cast<const half8*>(h1h + sn * H1C + halfk * 8);
    f32x4 acc = {0.f, 0.f, 0.f, 0.f};
    #pragma unroll
    for (int kk = 0; kk < 32; kk++) {
      _Float16 hv = h_lds[el][kk];
      half8 hsp;
      #pragma unroll
      for (int j = 0; j < 8; j++) hsp[j] = hv;
      half8 af = hsp * hsb;            // v_pk_mul_f16 x4
      half8 bfrag = *reinterpret_cast<const half8*>(&Bl[(kk * 64 + lane) * 8]);
      acc = __builtin_amdgcn_mfma_f32_16x16x32_f16(af, bfrag, acc, 0, 0, 0);
    }
    #pragma unroll
    for (int r = 0; r < 4; r++) {
      int row = halfk * 4 + r;
      int d = s_dst[eb + row];
      atomicAdd(&agg2[d * H2C + er], acc[r]);
    }
  }
}

// pooled[batch[n],o] += relu(agg2[n,o])
__global__ __launch_bounds__(256) void k_pool(const float* __restrict__ agg2,
    const int* __restrict__ batch, float* __restrict__ pooled) {
  int t = blockIdx.x * 256 + threadIdx.x;
  int n = t >> 4, o = t & 15;
  if (n >= NNODES) return;
  float v = agg2[n * H2C + o];
  v = v > 0.f ? v : 0.f;
  atomicAdd(&pooled[batch[n] * H2C + o], v);
}

// out[g] = relu(pooled[g]@fc1_w + fc1_b) @ out_w + out_b
__global__ __launch_bounds__(256) void k_head(const float* __restrict__ pooled,
    const float* __restrict__ fc1w, const float* __restrict__ fc1b,
    const float* __restrict__ outw, const float* __restrict__ outb,
    float* __restrict__ out) {
  int g = blockIdx.x * 256 + threadIdx.x;
  if (g >= NGRAPHS) return;
  float p[H2C];
  #pragma unroll
  for (int i = 0; i < H2C; i++) p[i] = pooled[g * H2C + i];
  float acc = outb[0];
  #pragma unroll
  for (int o = 0; o < H1C; o++) {
    float v = fc1b[o];
    #pragma unroll
    for (int i = 0; i < H2C; i++) v += p[i] * fc1w[i * H1C + o];
    v = v > 0.f ? v : 0.f;
    acc += v * outw[o];
  }
  out[g] = acc;
}

extern "C" void kernel_launch(void* const* d_in, const int* in_sizes, int n_in,
                              void* d_out, int out_size, void* d_ws, size_t ws_size,
                              hipStream_t stream) {
  const float* x      = (const float*)d_in[0];
  const int*   ei     = (const int*)d_in[1];
  const float* ea     = (const float*)d_in[2];
  const int*   batch  = (const int*)d_in[3];
  const float* c1w1   = (const float*)d_in[4];
  const float* c1b1   = (const float*)d_in[5];
  const float* c1w2   = (const float*)d_in[6];
  const float* c1b2   = (const float*)d_in[7];
  const float* c1root = (const float*)d_in[8];
  const float* c1bias = (const float*)d_in[9];
  const float* c2w1   = (const float*)d_in[10];
  const float* c2b1   = (const float*)d_in[11];
  const float* c2w2   = (const float*)d_in[12];
  const float* c2b2   = (const float*)d_in[13];
  const float* c2root = (const float*)d_in[14];
  const float* c2bias = (const float*)d_in[15];
  const float* fc1w   = (const float*)d_in[16];
  const float* fc1b   = (const float*)d_in[17];
  const float* outw   = (const float*)d_in[18];
  const float* outb   = (const float*)d_in[19];
  float* out = (float*)d_out;

  float*     agg1   = (float*)d_ws;                       // 12.8 MB
  _Float16*  h1h    = (_Float16*)(agg1 + NNODES * H1C);   // 6.4 MB
  float*     agg2   = (float*)(h1h + NNODES * H1C);       // 6.4 MB
  float*     pooled = agg2 + NNODES * H2C;                // 320 KB
  _Float16*  B2h    = (_Float16*)(pooled + NGRAPHS * H2C);// 32 KB
  _Float16*  B1h    = B2h + 32 * 64 * 8;                  // 24 KB

  hipMemsetAsync(pooled, 0, NGRAPHS * H2C * sizeof(float), stream);

  k_init1<<<(NNODES * H1C + 255) / 256, 256, 0, stream>>>(x, c1root, c1bias, agg1);
  k_prepB1<<<48, 256, 0, stream>>>(c1w2, c1b2, B1h);
  k_prepB2<<<64, 256, 0, stream>>>(c2w2, B2h);
  k_edge1_mfma<<<NEDGES / 256, 256, 0, stream>>>(x, ei, ea, c1w1, c1b1, B1h, agg1);
  k_mid<<<(NNODES * H2C + 255) / 256, 256, 0, stream>>>(agg1, c2root, c2bias, h1h, agg2);
  k_edge2_mfma<<<NEDGES / 256, 256, 0, stream>>>(h1h, ei, ea, c2w1, c2b1, B2h, agg2);
  k_pool<<<(NNODES * H2C + 255) / 256, 256, 0, stream>>>(agg2, batch, pooled);
  k_head<<<(NGRAPHS + 255) / 256, 256, 0, stream>>>(pooled, fc1w, fc1b, outw, outb, out);
}